// Round 3
// baseline (681.813 us; speedup 1.0000x reference)
//
#include <hip/hip_runtime.h>

#define SMP 64      // samples per block (= lanes per wave)
#define NW 16       // waves per block
#define NT (NW*64)
#define SLC 8       // hidden columns per wave slice (128/NW)

constexpr float DTc  = 0.02f;
constexpr float ADc  = (2.0f/3.0f)*0.02f;   // alpha*DT
constexpr float EPSc = 1e-6f;

// S (per-sample small state) field offsets, stride 171 (odd -> conflict-free)
#define FQ   0    // q (6)
#define FQD  6    // qdot (6)
#define FL   12   // 21 tril entries of L (y accumulator, init = b3L)
#define FM   33   // 36 full symmetric M
#define FU   69   // u = M qd (6)
#define FP   75   // p = L^T qd (6)
#define FR   81   // r = L^T u (6)
#define FDY  87   // dy: JVP of y along qd (21, atomic)
#define FDV  108  // dV/dq (6)
#define FGV  114  // V-grad wrt trig feats (12, atomic)
#define FGL  126  // c2-scalar grad wrt trig feats (12, atomic)
#define FC1  138  // c1 = B u + M B qd (6)
#define FKQ  144  // qddot of stage 1 (k1) (6)
#define FGY  150  // gy VJP seed (21, published by wv 3 in P4)
#define SSTR 171

#define HS 129    // odd stride for 128-vectors

__device__ __forceinline__ float softplusf(float z) {
    return fmaxf(z, 0.0f) + __logf(1.0f + __expf(-fabsf(z)));
}
__device__ __forceinline__ float sigmoidf_(float z) {
    float t = __expf(-fabsf(z));
    float r = 1.0f / (1.0f + t);
    return z >= 0.0f ? r : t * r;
}
__device__ __forceinline__ float dot8(const float4* w, const float* g) {
    float4 a = w[0], b = w[1];
    return g[0]*a.x + g[1]*a.y + g[2]*a.z + g[3]*a.w
         + g[4]*b.x + g[5]*b.y + g[6]*b.z + g[7]*b.w;
}
__device__ __forceinline__ void axpy8(float* acc, const float4* w, float h) {
    float4 a = w[0], b = w[1];
    acc[0] += h*a.x; acc[1] += h*a.y; acc[2] += h*a.z; acc[3] += h*a.w;
    acc[4] += h*b.x; acc[5] += h*b.y; acc[6] += h*b.z; acc[7] += h*b.w;
}
__device__ __forceinline__ float dot12(const float4* w, const float* v) {
    float4 a = w[0], b = w[1], c = w[2];
    return v[0]*a.x + v[1]*a.y + v[2]*a.z + v[3]*a.w
         + v[4]*b.x + v[5]*b.y + v[6]*b.z + v[7]*b.w
         + v[8]*c.x + v[9]*c.y + v[10]*c.z + v[11]*c.w;
}
__device__ __forceinline__ void axpy12(float* acc, const float4* w, float s) {
    float4 a = w[0], b = w[1], c = w[2];
    acc[0] += s*a.x; acc[1] += s*a.y; acc[2]  += s*a.z; acc[3]  += s*a.w;
    acc[4] += s*b.x; acc[5] += s*b.y; acc[6]  += s*b.z; acc[7]  += s*b.w;
    acc[8] += s*c.x; acc[9] += s*c.y; acc[10] += s*c.z; acc[11] += s*c.w;
}

__global__ void prep_kernel(const float* __restrict__ W1L, const float* __restrict__ W1V,
                            float* __restrict__ ws) {
    int idx = blockIdx.x*256 + threadIdx.x;
    if (idx < 1536) {                       // W1LT[n*12+d] = W1L[d*128+n]
        int n = idx / 12, d = idx % 12;
        ws[idx] = W1L[d*128 + n];
    } else if (idx < 3072) {                // W1VT[m*12+d] = W1V[d*128+m]
        int j = idx - 1536;
        int m = j / 12, d = j % 12;
        ws[idx] = W1V[d*128 + m];
    }
}

// amdgpu_waves_per_eu(4,4): pin the allocator's occupancy target to 4 waves/EU
// (the LDS footprint caps us at 1 block/CU = 16 waves = 4/EU anyway).
// Without it the backend targets 8/EU -> 64 VGPRs -> 44 MB scratch spill
// per dispatch (rounds 1-2, WRITE_SIZE counter).
__global__ __launch_bounds__(NT)
__attribute__((amdgpu_waves_per_eu(4, 4)))
void lnn_kernel(
    const float* __restrict__ o,   const float* __restrict__ aIn,
    const float* __restrict__ b1L, const float* __restrict__ W2L,
    const float* __restrict__ b2L, const float* __restrict__ W3L,
    const float* __restrict__ b3L,
    const float* __restrict__ b1V, const float* __restrict__ W2V,
    const float* __restrict__ b2V, const float* __restrict__ W3V,
    const float* __restrict__ W1LT, const float* __restrict__ W1VT,
    float* __restrict__ out)
{
    __shared__ float H1[SMP*HS];    // h1L = softplus(z1L), whole stage
    __shared__ float HVs[SMP*HS];   // h1V (P0-P2), then dh1 = JVP of h1L (P3-P4)
    __shared__ float G[SMP*HS];     // g2V (P1-P2), then gz2 (P4-P5)
    __shared__ float S[SMP*SSTR];

    const int tid  = threadIdx.x;
    const int lane = tid & 63;
    const int wv   = __builtin_amdgcn_readfirstlane(tid >> 6);
    const int gs   = blockIdx.x * SMP + lane;     // global sample of this lane
    const int n0   = __builtin_amdgcn_readfirstlane(wv * SLC);
    float* Sl    = &S[lane*SSTR];
    float* Hrow1 = &H1[lane*HS];
    float* HrowV = &HVs[lane*HS];
    float* HrowG = &G[lane*HS];

    constexpr int TRW[21] = {0,1,1,2,2,2,3,3,3,3,4,4,4,4,4,5,5,5,5,5,5};
    constexpr int TCW[21] = {0,0,1,0,1,2,0,1,2,3,0,1,2,3,4,0,1,2,3,4,5};

    float qd[6], tt[12];

    for (int stage = 0; stage < 2; ++stage) {
        // ---------------- P0: state load + trig + layer-1 (both nets, own slice) ----------------
        {
            float qv[6];
            if (stage == 0) {
                #pragma unroll
                for (int i = 0; i < 6; ++i) { qv[i] = o[gs*18+i]; qd[i] = o[gs*18+6+i]; }
                if (wv == 0) {
                    #pragma unroll
                    for (int i = 0; i < 6; ++i) { Sl[FQ+i] = qv[i]; Sl[FQD+i] = qd[i]; }
                }
            } else {
                #pragma unroll
                for (int i = 0; i < 6; ++i) { qv[i] = Sl[FQ+i]; qd[i] = Sl[FQD+i]; }
            }
            #pragma unroll
            for (int i = 0; i < 6; ++i) { tt[2*i] = cosf(qv[i]); tt[2*i+1] = sinf(qv[i]); }
        }
        if (wv == 1) {
            #pragma unroll
            for (int k = 0; k < 21; ++k) Sl[FL+k] = b3L[k];
        } else if (wv == 2) {
            #pragma unroll
            for (int k = 0; k < 21; ++k) Sl[FDY+k] = 0.0f;
        } else if (wv == 3) {
            #pragma unroll
            for (int d = 0; d < 12; ++d) { Sl[FGV+d] = 0.0f; Sl[FGL+d] = 0.0f; }
        }
        float h1reg[SLC];
        #pragma unroll
        for (int j = 0; j < SLC; ++j) {
            int m = n0 + j;
            float zL = b1L[m] + dot12((const float4*)&W1LT[m*12], tt);
            h1reg[j] = softplusf(zL);
            Hrow1[m] = h1reg[j];
            float zV = b1V[m] + dot12((const float4*)&W1VT[m*12], tt);
            HrowV[m] = softplusf(zV);
        }
        __syncthreads();

        // ---------------- P1: fused layer-2 (L and V), y partial, g2V seed ----------------
        float z2reg[SLC];   // z2L own slice, kept in registers until P4
        {
            float accL[SLC], accV[SLC];
            #pragma unroll
            for (int j = 0; j < SLC; ++j) { accL[j] = b2L[n0+j]; accV[j] = b2V[n0+j]; }
            for (int m8 = 0; m8 < 128; m8 += 8) {
                float h1r[8], hvr[8];
                #pragma unroll
                for (int t = 0; t < 8; ++t) { h1r[t] = Hrow1[m8+t]; hvr[t] = HrowV[m8+t]; }
                #pragma unroll
                for (int t = 0; t < 8; ++t) {
                    axpy8(accL, (const float4*)&W2L[(m8+t)*128 + n0], h1r[t]);
                    axpy8(accV, (const float4*)&W2V[(m8+t)*128 + n0], hvr[t]);
                }
            }
            float yp[21];
            #pragma unroll
            for (int k = 0; k < 21; ++k) yp[k] = 0.0f;
            #pragma unroll
            for (int j = 0; j < SLC; ++j) {
                int n = n0 + j;
                HrowG[n] = sigmoidf_(accV[j]) * W3V[n];   // g2V
                z2reg[j] = accL[j];
                float h2 = softplusf(accL[j]);
                const float* wr = &W3L[n*21];
                #pragma unroll
                for (int k = 0; k < 21; ++k) yp[k] += h2 * wr[k];
            }
            #pragma unroll
            for (int k = 0; k < 21; ++k) atomicAdd(&Sl[FL+k], yp[k]);
        }
        __syncthreads();

        // ---------------- P2: V backward (own m-slice): g1V -> gtV ----------------
        {
            float g1v[SLC];
            #pragma unroll
            for (int j = 0; j < SLC; ++j) g1v[j] = 0.0f;
            for (int nn = 0; nn < 128; nn += 8) {
                float gr[8];
                #pragma unroll
                for (int t = 0; t < 8; ++t) gr[t] = HrowG[nn+t];
                #pragma unroll
                for (int j = 0; j < SLC; ++j)
                    g1v[j] += dot8((const float4*)&W2V[(n0+j)*128 + nn], gr);
            }
            float gtv[12];
            #pragma unroll
            for (int d = 0; d < 12; ++d) gtv[d] = 0.0f;
            #pragma unroll
            for (int j = 0; j < SLC; ++j) {
                float g1h = g1v[j] * (1.0f - __expf(-HrowV[n0+j]));   // sigmoid(z1V)
                axpy12(gtv, (const float4*)&W1VT[(n0+j)*12], g1h);
            }
            #pragma unroll
            for (int d = 0; d < 12; ++d) atomicAdd(&Sl[FGV+d], gtv[d]);
        }
        __syncthreads();

        // ---------------- P3: dh1 (JVP layer-1) -> HV; roles: M,u,p,r / dV ----------------
        float s1l[SLC];
        {
            float dtv[12];
            #pragma unroll
            for (int i = 0; i < 6; ++i) { dtv[2*i] = -tt[2*i+1]*qd[i]; dtv[2*i+1] = tt[2*i]*qd[i]; }
            #pragma unroll
            for (int j = 0; j < SLC; ++j) {
                int m = n0 + j;
                float dz1 = dot12((const float4*)&W1LT[m*12], dtv);
                s1l[j] = 1.0f - __expf(-h1reg[j]);     // sigmoid(z1L)
                HrowV[m] = s1l[j] * dz1;               // dh1 (overwrites dead h1V)
            }
            if (wv == 0) {   // M = L L^T + eps I ; u = M qd ; p = L^T qd ; r = L^T u
                float Lv[21];
                #pragma unroll
                for (int t = 0; t < 21; ++t) Lv[t] = Sl[FL+t];
                #pragma unroll
                for (int i = 0; i < 6; ++i) {
                    #pragma unroll
                    for (int jj = 0; jj <= i; ++jj) {
                        float s = 0.0f;
                        #pragma unroll
                        for (int k = 0; k <= jj; ++k)
                            s += Lv[(i*(i+1))/2 + k] * Lv[(jj*(jj+1))/2 + k];
                        if (i == jj) s += EPSc;
                        Sl[FM + i*6 + jj] = s;
                        Sl[FM + jj*6 + i] = s;
                    }
                }
                float um[6];
                #pragma unroll
                for (int i = 0; i < 6; ++i) {
                    float s = 0.0f;
                    #pragma unroll
                    for (int jj = 0; jj < 6; ++jj) s += Sl[FM + i*6 + jj] * qd[jj];
                    um[i] = s; Sl[FU+i] = s;
                }
                float pv[6], rv[6];
                #pragma unroll
                for (int i = 0; i < 6; ++i) { pv[i] = 0.0f; rv[i] = 0.0f; }
                #pragma unroll
                for (int t = 0; t < 21; ++t) {
                    pv[TCW[t]] += Lv[t] * qd[TRW[t]];
                    rv[TCW[t]] += Lv[t] * um[TRW[t]];
                }
                #pragma unroll
                for (int i = 0; i < 6; ++i) { Sl[FP+i] = pv[i]; Sl[FR+i] = rv[i]; }
            } else if (wv == 1) {
                #pragma unroll
                for (int i = 0; i < 6; ++i)
                    Sl[FDV+i] = -tt[2*i+1]*Sl[FGV+2*i] + tt[2*i]*Sl[FGV+2*i+1];
            }
        }
        __syncthreads();

        // ---------------- P4: dz2 (JVP layer-2) -> dy atomic; gy publish; gz2 into G ----------
        {
            // wv 3 publishes gy = u p^T + qd r^T (tril) for this lane's sample.
            // Everyone else proceeds straight into the dz2 accumulation; the
            // mid-phase barrier below makes FGY visible before it is consumed.
            if (wv == 3) {
                float uu[6], pp[6], rr[6];
                #pragma unroll
                for (int i = 0; i < 6; ++i) { uu[i]=Sl[FU+i]; pp[i]=Sl[FP+i]; rr[i]=Sl[FR+i]; }
                #pragma unroll
                for (int t = 0; t < 21; ++t)
                    Sl[FGY+t] = uu[TRW[t]]*pp[TCW[t]] + qd[TRW[t]]*rr[TCW[t]];
            }
            float dz2[SLC];
            #pragma unroll
            for (int j = 0; j < SLC; ++j) dz2[j] = 0.0f;
            for (int m8 = 0; m8 < 128; m8 += 8) {
                float dr[8];
                #pragma unroll
                for (int t = 0; t < 8; ++t) dr[t] = HrowV[m8+t];
                #pragma unroll
                for (int t = 0; t < 8; ++t)
                    axpy8(dz2, (const float4*)&W2L[(m8+t)*128 + n0], dr[t]);
            }
            float sg2[SLC];
            #pragma unroll
            for (int j = 0; j < SLC; ++j) sg2[j] = sigmoidf_(z2reg[j]);
            float dyp[21];
            #pragma unroll
            for (int k = 0; k < 21; ++k) dyp[k] = 0.0f;
            #pragma unroll
            for (int j = 0; j < SLC; ++j) {
                float dh2 = sg2[j] * dz2[j];
                const float* wr = &W3L[(n0+j)*21];
                #pragma unroll
                for (int k = 0; k < 21; ++k) dyp[k] += dh2 * wr[k];
            }
            #pragma unroll
            for (int k = 0; k < 21; ++k) atomicAdd(&Sl[FDY+k], dyp[k]);
            __syncthreads();   // FGY visible; FDY complete for P5 reader
            float gyr[21];
            #pragma unroll
            for (int k = 0; k < 21; ++k) gyr[k] = Sl[FGY+k];
            #pragma unroll
            for (int j = 0; j < SLC; ++j) {
                const float* wr = &W3L[(n0+j)*21];
                float gh2 = 0.0f;
                #pragma unroll
                for (int k = 0; k < 21; ++k) gh2 += wr[k] * gyr[k];
                HrowG[n0+j] = sg2[j] * gh2;            // gz2 (overwrites dead g2V)
            }
        }
        __syncthreads();

        // ---------------- P5: VJP layer-1 -> gtL atomic; role: B, c1 ----------------
        {
            float gh1[SLC];
            #pragma unroll
            for (int j = 0; j < SLC; ++j) gh1[j] = 0.0f;
            for (int nn = 0; nn < 128; nn += 8) {
                float gr[8];
                #pragma unroll
                for (int t = 0; t < 8; ++t) gr[t] = HrowG[nn+t];
                #pragma unroll
                for (int j = 0; j < SLC; ++j)
                    gh1[j] += dot8((const float4*)&W2L[(n0+j)*128 + nn], gr);
            }
            float gtl[12];
            #pragma unroll
            for (int d = 0; d < 12; ++d) gtl[d] = 0.0f;
            #pragma unroll
            for (int j = 0; j < SLC; ++j) {
                float gz1 = s1l[j] * gh1[j];
                axpy12(gtl, (const float4*)&W1LT[(n0+j)*12], gz1);
            }
            #pragma unroll
            for (int d = 0; d < 12; ++d) atomicAdd(&Sl[FGL+d], gtl[d]);
            if (wv == 1) {   // B = dL L^T + L dL^T (lower tri only); c1 = B u + M B qd
                float Lv[21], dLv[21];
                #pragma unroll
                for (int t = 0; t < 21; ++t) { Lv[t] = Sl[FL+t]; dLv[t] = Sl[FDY+t]; }
                float Bl[21];   // lower triangle of symmetric B
                #pragma unroll
                for (int i = 0; i < 6; ++i) {
                    #pragma unroll
                    for (int jj = 0; jj <= i; ++jj) {
                        float s = 0.0f;
                        #pragma unroll
                        for (int k = 0; k <= jj; ++k)
                            s += dLv[(i*(i+1))/2+k]*Lv[(jj*(jj+1))/2+k]
                               + Lv[(i*(i+1))/2+k]*dLv[(jj*(jj+1))/2+k];
                        Bl[(i*(i+1))/2 + jj] = s;
                    }
                }
                float uu[6];
                #pragma unroll
                for (int i = 0; i < 6; ++i) uu[i] = Sl[FU+i];
                float Bq[6], Bu[6];
                #pragma unroll
                for (int i = 0; i < 6; ++i) {
                    float s1 = 0.0f, s2 = 0.0f;
                    #pragma unroll
                    for (int jj = 0; jj < 6; ++jj) {
                        float Bij = (jj <= i) ? Bl[(i*(i+1))/2 + jj] : Bl[(jj*(jj+1))/2 + i];
                        s1 += Bij*qd[jj]; s2 += Bij*uu[jj];
                    }
                    Bq[i] = s1; Bu[i] = s2;
                }
                #pragma unroll
                for (int i = 0; i < 6; ++i) {
                    float s = 0.0f;
                    #pragma unroll
                    for (int jj = 0; jj < 6; ++jj) s += Sl[FM+i*6+jj]*Bq[jj];
                    Sl[FC1+i] = Bu[i] + s;
                }
            }
        }
        __syncthreads();

        // ---------------- P6: epilogue (wave 0): c, rhs, inv(tril(M)), qddot, RK update --------
        if (wv == 0) {
            float rhs[6];
            #pragma unroll
            for (int i = 0; i < 6; ++i) {
                float c2i = 2.0f*(-tt[2*i+1]*Sl[FGL+2*i] + tt[2*i]*Sl[FGL+2*i+1]);
                float c = Sl[FC1+i] - 0.5f*c2i;
                rhs[i] = aIn[gs*6+i] - c - Sl[FDV+i];
            }
            // forward-substitution columns of inv(tril(M)); M read directly from LDS
            float Li[21];
            #pragma unroll
            for (int j = 0; j < 6; ++j) {
                float x[6];
                x[j] = 1.0f / Sl[FM + j*6 + j];
                #pragma unroll
                for (int i2 = j+1; i2 < 6; ++i2) {
                    float s = 0.0f;
                    #pragma unroll
                    for (int k = j; k < i2; ++k) s += Sl[FM + i2*6 + k]*x[k];
                    x[i2] = -s / Sl[FM + i2*6 + i2];
                }
                #pragma unroll
                for (int i2 = j; i2 < 6; ++i2) Li[(i2*(i2+1))/2 + j] = x[i2];
            }
            float y1[6];
            #pragma unroll
            for (int i = 0; i < 6; ++i) {
                float s = 0.0f;
                #pragma unroll
                for (int j = 0; j <= i; ++j) s += Li[(i*(i+1))/2+j]*rhs[j];
                y1[i] = s;
            }
            float qdd2[6];
            #pragma unroll
            for (int i = 0; i < 6; ++i) {
                float s = 0.0f;
                #pragma unroll
                for (int k = i; k < 6; ++k) s += Li[(k*(k+1))/2+i]*y1[k];
                qdd2[i] = s;
            }
            if (stage == 0) {
                #pragma unroll
                for (int i = 0; i < 6; ++i) {
                    Sl[FKQ+i] = qdd2[i];
                    Sl[FQ+i]  = Sl[FQ+i] + ADc*qd[i];
                    Sl[FQD+i] = qd[i] + ADc*qdd2[i];
                }
            } else {
                #pragma unroll
                for (int i = 0; i < 6; ++i) {
                    float q0 = o[gs*18+i], qd0 = o[gs*18+6+i];
                    out[gs*18+i]    = q0  + DTc*(0.25f*qd0 + 0.75f*qd[i]);
                    out[gs*18+6+i]  = qd0 + DTc*(0.25f*Sl[FKQ+i] + 0.75f*qdd2[i]);
                    out[gs*18+12+i] = o[gs*18+12+i];
                }
            }
        }
        __syncthreads();
    }
}

extern "C" void kernel_launch(void* const* d_in, const int* in_sizes, int n_in,
                              void* d_out, int out_size, void* d_ws, size_t ws_size,
                              hipStream_t stream) {
    const float* o   = (const float*)d_in[0];
    const float* a   = (const float*)d_in[1];
    const float* W1L = (const float*)d_in[2];
    const float* b1L = (const float*)d_in[3];
    const float* W2L = (const float*)d_in[4];
    const float* b2L = (const float*)d_in[5];
    const float* W3L = (const float*)d_in[6];
    const float* b3L = (const float*)d_in[7];
    const float* W1V = (const float*)d_in[8];
    const float* b1V = (const float*)d_in[9];
    const float* W2V = (const float*)d_in[10];
    const float* b2V = (const float*)d_in[11];
    const float* W3V = (const float*)d_in[12];
    float* ws   = (float*)d_ws;
    float* outp = (float*)d_out;

    hipLaunchKernelGGL(prep_kernel, dim3(12), dim3(256), 0, stream, W1L, W1V, ws);
    hipLaunchKernelGGL(lnn_kernel, dim3(32768/SMP), dim3(NT), 0, stream,
        o, a, b1L, W2L, b2L, W3L, b3L, b1V, W2V, b2V, W3V,
        ws, ws + 1536, outp);
}

// Round 4
// 605.749 us; speedup vs baseline: 1.1256x; 1.1256x over previous
//
#include <hip/hip_runtime.h>

#define SMP 64      // samples per block (= lanes per wave)
#define NW 8        // waves per block  (512 threads: the ONLY shape the backend
                    //  allocates >64 VGPRs for; 1024-thread builds clamp to 64
                    //  and spill 44 MB/dispatch — rounds 1-3)
#define NT (NW*64)
#define SLC 16      // hidden columns per wave slice (128/NW)

constexpr float DTc  = 0.02f;
constexpr float ADc  = (2.0f/3.0f)*0.02f;   // alpha*DT
constexpr float EPSc = 1e-6f;

// S (per-sample small state) field offsets, stride 151 (odd -> conflict-free)
#define FQ   0    // q (6)
#define FQD  6    // qdot (6)
#define FL   12   // 21 tril entries of L (y accumulator, init = b3L)
#define FM   33   // 36 full symmetric M
#define FU   69   // u = M qd (6)
#define FP   75   // p = L^T qd (6)
#define FR   81   // r = L^T u (6)
#define FDY  87   // dy: JVP of y along qd (21, atomic)
#define FDV  108  // dV/dq (6)
#define FGV  114  // V-grad wrt trig feats (12, atomic)
#define FGL  126  // c2-scalar grad wrt trig feats (12, atomic)
#define FC1  138  // c1 = B u + M B qd (6)
#define FKQ  144  // qddot of stage 1 (k1) (6)
#define SSTR 151

#define HS 129    // odd stride for 128-vectors

__device__ __forceinline__ float softplusf(float z) {
    return fmaxf(z, 0.0f) + __logf(1.0f + __expf(-fabsf(z)));
}
__device__ __forceinline__ float sigmoidf_(float z) {
    float t = __expf(-fabsf(z));
    float r = 1.0f / (1.0f + t);
    return z >= 0.0f ? r : t * r;
}
__device__ __forceinline__ float dot8(const float4* w, const float* g) {
    float4 a = w[0], b = w[1];
    return g[0]*a.x + g[1]*a.y + g[2]*a.z + g[3]*a.w
         + g[4]*b.x + g[5]*b.y + g[6]*b.z + g[7]*b.w;
}
__device__ __forceinline__ void axpy16(float* acc, const float4* w, float h) {
    #pragma unroll
    for (int g = 0; g < 4; ++g) {
        float4 v = w[g];
        acc[4*g+0] += h*v.x; acc[4*g+1] += h*v.y;
        acc[4*g+2] += h*v.z; acc[4*g+3] += h*v.w;
    }
}
__device__ __forceinline__ float dot12(const float4* w, const float* v) {
    float4 a = w[0], b = w[1], c = w[2];
    return v[0]*a.x + v[1]*a.y + v[2]*a.z + v[3]*a.w
         + v[4]*b.x + v[5]*b.y + v[6]*b.z + v[7]*b.w
         + v[8]*c.x + v[9]*c.y + v[10]*c.z + v[11]*c.w;
}
__device__ __forceinline__ void axpy12(float* acc, const float4* w, float s) {
    float4 a = w[0], b = w[1], c = w[2];
    acc[0] += s*a.x; acc[1] += s*a.y; acc[2]  += s*a.z; acc[3]  += s*a.w;
    acc[4] += s*b.x; acc[5] += s*b.y; acc[6]  += s*b.z; acc[7]  += s*b.w;
    acc[8] += s*c.x; acc[9] += s*c.y; acc[10] += s*c.z; acc[11] += s*c.w;
}

__global__ void prep_kernel(const float* __restrict__ W1L, const float* __restrict__ W1V,
                            float* __restrict__ ws) {
    int idx = blockIdx.x*256 + threadIdx.x;
    if (idx < 1536) {                       // W1LT[n*12+d] = W1L[d*128+n]
        int n = idx / 12, d = idx % 12;
        ws[idx] = W1L[d*128 + n];
    } else if (idx < 3072) {                // W1VT[m*12+d] = W1V[d*128+m]
        int j = idx - 1536;
        int m = j / 12, d = j % 12;
        ws[idx] = W1V[d*128 + m];
    }
}

// (NT,2) = round-0's exact attribute config: empirically yields a sane VGPR
// allocation (116) instead of the 64-VGPR/44MB-spill pathology of 1024-thread
// builds. LDS 137.7KB -> 1 WG/CU -> 2 waves/SIMD; VGPR budget 256 -> no spill.
__launch_bounds__(NT, 2)
__global__ void lnn_kernel(
    const float* __restrict__ o,   const float* __restrict__ aIn,
    const float* __restrict__ b1L, const float* __restrict__ W2L,
    const float* __restrict__ b2L, const float* __restrict__ W3L,
    const float* __restrict__ b3L,
    const float* __restrict__ b1V, const float* __restrict__ W2V,
    const float* __restrict__ b2V, const float* __restrict__ W3V,
    const float* __restrict__ W1LT, const float* __restrict__ W1VT,
    float* __restrict__ out)
{
    __shared__ float H1[SMP*HS];    // h1L = softplus(z1L), whole stage
    __shared__ float HVs[SMP*HS];   // h1V (P0-P2), then dh1 = JVP of h1L (P3-P4)
    __shared__ float G[SMP*HS];     // g2V (P1-P2), then gz2 (P4-P5)
    __shared__ float S[SMP*SSTR];

    const int tid  = threadIdx.x;
    const int lane = tid & 63;
    const int wv   = __builtin_amdgcn_readfirstlane(tid >> 6);
    const int gs   = blockIdx.x * SMP + lane;     // global sample of this lane
    const int n0   = __builtin_amdgcn_readfirstlane(wv * SLC);
    float* Sl    = &S[lane*SSTR];
    float* Hrow1 = &H1[lane*HS];
    float* HrowV = &HVs[lane*HS];
    float* HrowG = &G[lane*HS];

    constexpr int TRW[21] = {0,1,1,2,2,2,3,3,3,3,4,4,4,4,4,5,5,5,5,5,5};
    constexpr int TCW[21] = {0,0,1,0,1,2,0,1,2,3,0,1,2,3,4,0,1,2,3,4,5};

    float qd[6], tt[12];

    for (int stage = 0; stage < 2; ++stage) {
        // ---------------- P0: state load + trig + layer-1 (both nets, own slice) ----------------
        {
            float qv[6];
            if (stage == 0) {
                #pragma unroll
                for (int i = 0; i < 6; ++i) { qv[i] = o[gs*18+i]; qd[i] = o[gs*18+6+i]; }
                if (wv == 0) {
                    #pragma unroll
                    for (int i = 0; i < 6; ++i) { Sl[FQ+i] = qv[i]; Sl[FQD+i] = qd[i]; }
                }
            } else {
                #pragma unroll
                for (int i = 0; i < 6; ++i) { qv[i] = Sl[FQ+i]; qd[i] = Sl[FQD+i]; }
            }
            #pragma unroll
            for (int i = 0; i < 6; ++i) { tt[2*i] = cosf(qv[i]); tt[2*i+1] = sinf(qv[i]); }
        }
        if (wv == 1) {
            #pragma unroll
            for (int k = 0; k < 21; ++k) Sl[FL+k] = b3L[k];
        } else if (wv == 2) {
            #pragma unroll
            for (int k = 0; k < 21; ++k) Sl[FDY+k] = 0.0f;
        } else if (wv == 3) {
            #pragma unroll
            for (int d = 0; d < 12; ++d) { Sl[FGV+d] = 0.0f; Sl[FGL+d] = 0.0f; }
        }
        float h1reg[SLC];
        #pragma unroll
        for (int j = 0; j < SLC; ++j) {
            int m = n0 + j;
            float zL = b1L[m] + dot12((const float4*)&W1LT[m*12], tt);
            h1reg[j] = softplusf(zL);
            Hrow1[m] = h1reg[j];
            float zV = b1V[m] + dot12((const float4*)&W1VT[m*12], tt);
            HrowV[m] = softplusf(zV);
        }
        __syncthreads();

        // ---------------- P1: fused layer-2 (L and V), y partial, g2V seed ----------------
        float z2reg[SLC];   // z2L own slice, kept in registers until P4
        {
            float accL[SLC], accV[SLC];
            #pragma unroll
            for (int j = 0; j < SLC; ++j) { accL[j] = b2L[n0+j]; accV[j] = b2V[n0+j]; }
            for (int m8 = 0; m8 < 128; m8 += 8) {
                float h1r[8], hvr[8];
                #pragma unroll
                for (int t = 0; t < 8; ++t) { h1r[t] = Hrow1[m8+t]; hvr[t] = HrowV[m8+t]; }
                #pragma unroll
                for (int t = 0; t < 8; ++t) {
                    axpy16(accL, (const float4*)&W2L[(m8+t)*128 + n0], h1r[t]);
                    axpy16(accV, (const float4*)&W2V[(m8+t)*128 + n0], hvr[t]);
                }
            }
            float yp[21];
            #pragma unroll
            for (int k = 0; k < 21; ++k) yp[k] = 0.0f;
            #pragma unroll
            for (int j = 0; j < SLC; ++j) {
                int n = n0 + j;
                HrowG[n] = sigmoidf_(accV[j]) * W3V[n];   // g2V
                z2reg[j] = accL[j];
                float h2 = softplusf(accL[j]);
                const float* wr = &W3L[n*21];
                #pragma unroll
                for (int k = 0; k < 21; ++k) yp[k] += h2 * wr[k];
            }
            #pragma unroll
            for (int k = 0; k < 21; ++k) atomicAdd(&Sl[FL+k], yp[k]);
        }
        __syncthreads();

        // ---------------- P2: V backward (own m-slice): g1V -> gtV ----------------
        {
            float g1v[SLC];
            #pragma unroll
            for (int j = 0; j < SLC; ++j) g1v[j] = 0.0f;
            for (int nn = 0; nn < 128; nn += 8) {
                float gr[8];
                #pragma unroll
                for (int t = 0; t < 8; ++t) gr[t] = HrowG[nn+t];
                #pragma unroll
                for (int j = 0; j < SLC; ++j)
                    g1v[j] += dot8((const float4*)&W2V[(n0+j)*128 + nn], gr);
            }
            float gtv[12];
            #pragma unroll
            for (int d = 0; d < 12; ++d) gtv[d] = 0.0f;
            #pragma unroll
            for (int j = 0; j < SLC; ++j) {
                float g1h = g1v[j] * (1.0f - __expf(-HrowV[n0+j]));   // sigmoid(z1V)
                axpy12(gtv, (const float4*)&W1VT[(n0+j)*12], g1h);
            }
            #pragma unroll
            for (int d = 0; d < 12; ++d) atomicAdd(&Sl[FGV+d], gtv[d]);
        }
        __syncthreads();

        // ---------------- P3: dh1 (JVP layer-1) -> HV; roles: M,u,p,r / dV ----------------
        float s1l[SLC];
        {
            float dtv[12];
            #pragma unroll
            for (int i = 0; i < 6; ++i) { dtv[2*i] = -tt[2*i+1]*qd[i]; dtv[2*i+1] = tt[2*i]*qd[i]; }
            #pragma unroll
            for (int j = 0; j < SLC; ++j) {
                int m = n0 + j;
                float dz1 = dot12((const float4*)&W1LT[m*12], dtv);
                s1l[j] = 1.0f - __expf(-h1reg[j]);     // sigmoid(z1L)
                HrowV[m] = s1l[j] * dz1;               // dh1 (overwrites dead h1V)
            }
            if (wv == 0) {   // M = L L^T + eps I ; u = M qd ; p = L^T qd ; r = L^T u
                float Lv[21];
                #pragma unroll
                for (int t = 0; t < 21; ++t) Lv[t] = Sl[FL+t];
                #pragma unroll
                for (int i = 0; i < 6; ++i) {
                    #pragma unroll
                    for (int jj = 0; jj <= i; ++jj) {
                        float s = 0.0f;
                        #pragma unroll
                        for (int k = 0; k <= jj; ++k)
                            s += Lv[(i*(i+1))/2 + k] * Lv[(jj*(jj+1))/2 + k];
                        if (i == jj) s += EPSc;
                        Sl[FM + i*6 + jj] = s;
                        Sl[FM + jj*6 + i] = s;
                    }
                }
                float um[6];
                #pragma unroll
                for (int i = 0; i < 6; ++i) {
                    float s = 0.0f;
                    #pragma unroll
                    for (int jj = 0; jj < 6; ++jj) s += Sl[FM + i*6 + jj] * qd[jj];
                    um[i] = s; Sl[FU+i] = s;
                }
                float pv[6], rv[6];
                #pragma unroll
                for (int i = 0; i < 6; ++i) { pv[i] = 0.0f; rv[i] = 0.0f; }
                #pragma unroll
                for (int t = 0; t < 21; ++t) {
                    pv[TCW[t]] += Lv[t] * qd[TRW[t]];
                    rv[TCW[t]] += Lv[t] * um[TRW[t]];
                }
                #pragma unroll
                for (int i = 0; i < 6; ++i) { Sl[FP+i] = pv[i]; Sl[FR+i] = rv[i]; }
            } else if (wv == 1) {
                #pragma unroll
                for (int i = 0; i < 6; ++i)
                    Sl[FDV+i] = -tt[2*i+1]*Sl[FGV+2*i] + tt[2*i]*Sl[FGV+2*i+1];
            }
        }
        __syncthreads();

        // ---------------- P4: dz2 (JVP layer-2) -> dy atomic; gh2 -> gz2 into G ----------------
        {
            float dz2[SLC];
            #pragma unroll
            for (int j = 0; j < SLC; ++j) dz2[j] = 0.0f;
            for (int m8 = 0; m8 < 128; m8 += 8) {
                float dr[8];
                #pragma unroll
                for (int t = 0; t < 8; ++t) dr[t] = HrowV[m8+t];
                #pragma unroll
                for (int t = 0; t < 8; ++t)
                    axpy16(dz2, (const float4*)&W2L[(m8+t)*128 + n0], dr[t]);
            }
            float sg2[SLC];
            #pragma unroll
            for (int j = 0; j < SLC; ++j) sg2[j] = sigmoidf_(z2reg[j]);
            float dyp[21];
            #pragma unroll
            for (int k = 0; k < 21; ++k) dyp[k] = 0.0f;
            #pragma unroll
            for (int j = 0; j < SLC; ++j) {
                float dh2 = sg2[j] * dz2[j];
                const float* wr = &W3L[(n0+j)*21];
                #pragma unroll
                for (int k = 0; k < 21; ++k) dyp[k] += dh2 * wr[k];
            }
            #pragma unroll
            for (int k = 0; k < 21; ++k) atomicAdd(&Sl[FDY+k], dyp[k]);
            // VJP seed: gy[t] = u[R]p[C] + qd[R]r[C]; gh2 = W3L gy; gz2 -> G
            // (computed AFTER the dyp atomics so gy[21] doesn't overlap dyp[21] liveness)
            float gy[21];
            {
                float uu[6], pp[6], rr[6];
                #pragma unroll
                for (int i = 0; i < 6; ++i) { uu[i]=Sl[FU+i]; pp[i]=Sl[FP+i]; rr[i]=Sl[FR+i]; }
                #pragma unroll
                for (int t = 0; t < 21; ++t)
                    gy[t] = uu[TRW[t]]*pp[TCW[t]] + qd[TRW[t]]*rr[TCW[t]];
            }
            #pragma unroll
            for (int j = 0; j < SLC; ++j) {
                const float* wr = &W3L[(n0+j)*21];
                float gh2 = 0.0f;
                #pragma unroll
                for (int k = 0; k < 21; ++k) gh2 += wr[k] * gy[k];
                HrowG[n0+j] = sg2[j] * gh2;            // gz2 (overwrites dead g2V)
            }
        }
        __syncthreads();

        // ---------------- P5: VJP layer-1 -> gtL atomic; role: B, c1 ----------------
        {
            float gh1[SLC];
            #pragma unroll
            for (int j = 0; j < SLC; ++j) gh1[j] = 0.0f;
            for (int nn = 0; nn < 128; nn += 8) {
                float gr[8];
                #pragma unroll
                for (int t = 0; t < 8; ++t) gr[t] = HrowG[nn+t];
                #pragma unroll
                for (int j = 0; j < SLC; ++j)
                    gh1[j] += dot8((const float4*)&W2L[(n0+j)*128 + nn], gr);
            }
            float gtl[12];
            #pragma unroll
            for (int d = 0; d < 12; ++d) gtl[d] = 0.0f;
            #pragma unroll
            for (int j = 0; j < SLC; ++j) {
                float gz1 = s1l[j] * gh1[j];
                axpy12(gtl, (const float4*)&W1LT[(n0+j)*12], gz1);
            }
            #pragma unroll
            for (int d = 0; d < 12; ++d) atomicAdd(&Sl[FGL+d], gtl[d]);
            if (wv == 1) {   // B = dL L^T + L dL^T (lower tri only); c1 = B u + M B qd
                float Lv[21], dLv[21];
                #pragma unroll
                for (int t = 0; t < 21; ++t) { Lv[t] = Sl[FL+t]; dLv[t] = Sl[FDY+t]; }
                float Bl[21];   // lower triangle of symmetric B
                #pragma unroll
                for (int i = 0; i < 6; ++i) {
                    #pragma unroll
                    for (int jj = 0; jj <= i; ++jj) {
                        float s = 0.0f;
                        #pragma unroll
                        for (int k = 0; k <= jj; ++k)
                            s += dLv[(i*(i+1))/2+k]*Lv[(jj*(jj+1))/2+k]
                               + Lv[(i*(i+1))/2+k]*dLv[(jj*(jj+1))/2+k];
                        Bl[(i*(i+1))/2 + jj] = s;
                    }
                }
                float uu[6];
                #pragma unroll
                for (int i = 0; i < 6; ++i) uu[i] = Sl[FU+i];
                float Bq[6], Bu[6];
                #pragma unroll
                for (int i = 0; i < 6; ++i) {
                    float s1 = 0.0f, s2 = 0.0f;
                    #pragma unroll
                    for (int jj = 0; jj < 6; ++jj) {
                        float Bij = (jj <= i) ? Bl[(i*(i+1))/2 + jj] : Bl[(jj*(jj+1))/2 + i];
                        s1 += Bij*qd[jj]; s2 += Bij*uu[jj];
                    }
                    Bq[i] = s1; Bu[i] = s2;
                }
                #pragma unroll
                for (int i = 0; i < 6; ++i) {
                    float s = 0.0f;
                    #pragma unroll
                    for (int jj = 0; jj < 6; ++jj) s += Sl[FM+i*6+jj]*Bq[jj];
                    Sl[FC1+i] = Bu[i] + s;
                }
            }
        }
        __syncthreads();

        // ---------------- P6: epilogue (wave 0): c, rhs, inv(tril(M)), qddot, RK update --------
        if (wv == 0) {
            float rhs[6];
            #pragma unroll
            for (int i = 0; i < 6; ++i) {
                float c2i = 2.0f*(-tt[2*i+1]*Sl[FGL+2*i] + tt[2*i]*Sl[FGL+2*i+1]);
                float c = Sl[FC1+i] - 0.5f*c2i;
                rhs[i] = aIn[gs*6+i] - c - Sl[FDV+i];
            }
            // forward-substitution columns of inv(tril(M)); M read directly from LDS
            float Li[21];
            #pragma unroll
            for (int j = 0; j < 6; ++j) {
                float x[6];
                x[j] = 1.0f / Sl[FM + j*6 + j];
                #pragma unroll
                for (int i2 = j+1; i2 < 6; ++i2) {
                    float s = 0.0f;
                    #pragma unroll
                    for (int k = j; k < i2; ++k) s += Sl[FM + i2*6 + k]*x[k];
                    x[i2] = -s / Sl[FM + i2*6 + i2];
                }
                #pragma unroll
                for (int i2 = j; i2 < 6; ++i2) Li[(i2*(i2+1))/2 + j] = x[i2];
            }
            float y1[6];
            #pragma unroll
            for (int i = 0; i < 6; ++i) {
                float s = 0.0f;
                #pragma unroll
                for (int j = 0; j <= i; ++j) s += Li[(i*(i+1))/2+j]*rhs[j];
                y1[i] = s;
            }
            float qdd2[6];
            #pragma unroll
            for (int i = 0; i < 6; ++i) {
                float s = 0.0f;
                #pragma unroll
                for (int k = i; k < 6; ++k) s += Li[(k*(k+1))/2+i]*y1[k];
                qdd2[i] = s;
            }
            if (stage == 0) {
                #pragma unroll
                for (int i = 0; i < 6; ++i) {
                    Sl[FKQ+i] = qdd2[i];
                    Sl[FQ+i]  = Sl[FQ+i] + ADc*qd[i];
                    Sl[FQD+i] = qd[i] + ADc*qdd2[i];
                }
            } else {
                #pragma unroll
                for (int i = 0; i < 6; ++i) {
                    float q0 = o[gs*18+i], qd0 = o[gs*18+6+i];
                    out[gs*18+i]    = q0  + DTc*(0.25f*qd0 + 0.75f*qd[i]);
                    out[gs*18+6+i]  = qd0 + DTc*(0.25f*Sl[FKQ+i] + 0.75f*qdd2[i]);
                    out[gs*18+12+i] = o[gs*18+12+i];
                }
            }
        }
        __syncthreads();
    }
}

extern "C" void kernel_launch(void* const* d_in, const int* in_sizes, int n_in,
                              void* d_out, int out_size, void* d_ws, size_t ws_size,
                              hipStream_t stream) {
    const float* o   = (const float*)d_in[0];
    const float* a   = (const float*)d_in[1];
    const float* W1L = (const float*)d_in[2];
    const float* b1L = (const float*)d_in[3];
    const float* W2L = (const float*)d_in[4];
    const float* b2L = (const float*)d_in[5];
    const float* W3L = (const float*)d_in[6];
    const float* b3L = (const float*)d_in[7];
    const float* W1V = (const float*)d_in[8];
    const float* b1V = (const float*)d_in[9];
    const float* W2V = (const float*)d_in[10];
    const float* b2V = (const float*)d_in[11];
    const float* W3V = (const float*)d_in[12];
    float* ws   = (float*)d_ws;
    float* outp = (float*)d_out;

    hipLaunchKernelGGL(prep_kernel, dim3(12), dim3(256), 0, stream, W1L, W1V, ws);
    hipLaunchKernelGGL(lnn_kernel, dim3(32768/SMP), dim3(NT), 0, stream,
        o, a, b1L, W2L, b2L, W3L, b3L, b1V, W2V, b2V, W3V,
        ws, ws + 1536, outp);
}